// Round 2
// baseline (1605.660 us; speedup 1.0000x reference)
//
#include <hip/hip_runtime.h>
#include <stdint.h>

#define NT 8192      // tokens
#define DM 1024      // d_model
#define DF 2048      // d_ff

typedef __attribute__((ext_vector_type(8))) short short8;
typedef __attribute__((ext_vector_type(4))) float f32x4;

__device__ __forceinline__ unsigned short f2bf(float f) {
  uint32_t x = __float_as_uint(f);
  return (unsigned short)((x + 0x7fffu + ((x >> 16) & 1u)) >> 16);
}

__device__ __forceinline__ void gload16(const void* g, void* l) {
  __builtin_amdgcn_global_load_lds(
      (const __attribute__((address_space(1))) uint32_t*)g,
      (__attribute__((address_space(3))) uint32_t*)l, 16, 0, 0);
}

// ---------------- fp32 -> bf16 (RNE) ----------------
__global__ void k_cvt(const float4* __restrict__ src, ushort4* __restrict__ dst, int n4) {
  int i = blockIdx.x * blockDim.x + threadIdx.x;
  int st = gridDim.x * blockDim.x;
  for (; i < n4; i += st) {
    float4 v = src[i];
    ushort4 o;
    o.x = f2bf(v.x); o.y = f2bf(v.y); o.z = f2bf(v.z); o.w = f2bf(v.w);
    dst[i] = o;
  }
}

// ---------------- router: logits, softmax, top2, losses ----------------
__global__ void k_router(const float* __restrict__ x, const float* __restrict__ wr,
                         int* cntb, int* cnt1, float* imp, float* z2,
                         int* epack, float2* gts) {
  int lane = threadIdx.x & 63;
  int wid = threadIdx.x >> 6;
  int t = blockIdx.x * 4 + wid;
  const float4* x4 = (const float4*)(x + (size_t)t * DM);
  const float4* w4 = (const float4*)wr;
  float p[8];
  #pragma unroll
  for (int e = 0; e < 8; ++e) p[e] = 0.f;
  #pragma unroll
  for (int j = 0; j < 4; ++j) {
    float4 xv = x4[lane + 64 * j];
    #pragma unroll
    for (int e = 0; e < 8; ++e) {
      float4 wv = w4[e * 256 + lane + 64 * j];
      p[e] += xv.x * wv.x + xv.y * wv.y + xv.z * wv.z + xv.w * wv.w;
    }
  }
  #pragma unroll
  for (int off = 32; off > 0; off >>= 1) {
    #pragma unroll
    for (int e = 0; e < 8; ++e) p[e] += __shfl_down(p[e], off);
  }
  if (lane == 0) {
    float m = p[0];
    #pragma unroll
    for (int e = 1; e < 8; ++e) m = fmaxf(m, p[e]);
    float pr[8], s = 0.f;
    #pragma unroll
    for (int e = 0; e < 8; ++e) { pr[e] = expf(p[e] - m); s += pr[e]; }
    float inv = 1.f / s;
    #pragma unroll
    for (int e = 0; e < 8; ++e) pr[e] *= inv;
    float z = m + logf(s);
    int e0 = 0; float b0 = p[0];
    #pragma unroll
    for (int e = 1; e < 8; ++e) { if (p[e] > b0) { b0 = p[e]; e0 = e; } }
    int e1 = -1; float b1 = -1e30f;
    #pragma unroll
    for (int e = 0; e < 8; ++e) { if (e != e0 && p[e] > b1) { b1 = p[e]; e1 = e; } }
    float p0 = 0.f, p1 = 0.f;
    #pragma unroll
    for (int e = 0; e < 8; ++e) {
      p0 = (e == e0) ? pr[e] : p0;
      p1 = (e == e1) ? pr[e] : p1;
    }
    float gs = p0 + p1 + 1e-9f;
    epack[t] = e0 | (e1 << 16);
    gts[t] = make_float2(p0 / gs, p1 / gs);
    atomicAdd(&cntb[e0], 1);
    atomicAdd(&cntb[e1], 1);
    atomicAdd(&cnt1[e0], 1);
    atomicAdd(z2, z * z);
    #pragma unroll
    for (int e = 0; e < 8; ++e) atomicAdd(&imp[e], pr[e]);
  }
}

// ---------------- offsets + scalar losses ----------------
__global__ void k_finalize(const int* cntb, const int* cnt1, const float* imp,
                           const float* z2, int* offs, float* otail) {
  if (threadIdx.x == 0 && blockIdx.x == 0) {
    int o = 0;
    for (int e = 0; e < 8; ++e) { offs[e] = o; o += cntb[e]; }
    otail[0] = 1e-3f * z2[0] / (float)NT;
    float aux = 0.f;
    for (int e = 0; e < 8; ++e)
      aux += (imp[e] / (float)NT) * ((float)cnt1[e] / (float)NT);
    otail[1] = aux * 8.f;
  }
}

// ---------------- deterministic stable scatter: 1 wave per expert ----------------
// Sequence j = 2*t + which (which: 0=top1, 1=top2). Stable rank via
// ballot prefix-scan -> identical bucket layout on every call.
__global__ void k_scatter(const int* __restrict__ epack, const float2* __restrict__ gts,
                          const int* __restrict__ offs,
                          int* __restrict__ btok, int* __restrict__ pos) {
  int e = blockIdx.x;
  int lane = threadIdx.x;
  int base = offs[e];
  int run = 0;
  for (int j0 = 0; j0 < 2 * NT; j0 += 64) {
    int j = j0 + lane;
    int t = j >> 1;
    int ep = epack[t];
    int sel = (j & 1) ? (ep >> 16) : (ep & 0xffff);
    bool f = (sel == e);
    unsigned long long m = __ballot(f);
    int rank = __popcll(m & ((1ull << lane) - 1ull));
    if (f) {
      int slot = base + run + rank;
      btok[slot] = t;
      pos[j] = slot;
    }
    run += __popcll(m);
  }
}

// ---------------- FFN pass 1: Hg = silu(Xg*W1^T) * (Xg*W3^T) ----------------
__global__ __launch_bounds__(256) void k_ffn1(
    const unsigned short* __restrict__ xb,
    const unsigned short* __restrict__ w1b,
    const unsigned short* __restrict__ w3b,
    const int* __restrict__ offs, const int* __restrict__ cnts,
    const int* __restrict__ btok,
    unsigned short* __restrict__ hg) {
  int e = blockIdx.z;
  int cnt = cnts[e];
  int m0 = blockIdx.y * 128;
  if (m0 >= cnt) return;
  int n0 = blockIdx.x * 128;
  int off = offs[e];
  __shared__ __align__(16) short As[128 * 64];
  __shared__ __align__(16) short B1s[128 * 64];
  __shared__ __align__(16) short B3s[128 * 64];
  __shared__ int tok[128];
  int tid = threadIdx.x, lane = tid & 63, wid = tid >> 6;
  if (tid < 128) {
    int r = m0 + tid; if (r > cnt - 1) r = cnt - 1;
    tok[tid] = btok[off + r];
  }
  __syncthreads();
  int srow = lane >> 3;
  int skk = (lane & 7) * 8;
  const unsigned short* w1e = w1b + (size_t)e * DF * DM;
  const unsigned short* w3e = w3b + (size_t)e * DF * DM;
  int wm = wid >> 1, wn = wid & 1;
  f32x4 acc1[4][4] = {};
  f32x4 acc3[4][4] = {};
  for (int kt = 0; kt < DM / 64; ++kt) {
    int k0 = kt * 64;
    #pragma unroll
    for (int c4 = 0; c4 < 4; ++c4) {
      int c = wid * 4 + c4;
      int row = c * 8 + srow;
      gload16(xb + (size_t)tok[row] * DM + k0 + skk, &As[c * 512]);
      gload16(w1e + (size_t)(n0 + row) * DM + k0 + skk, &B1s[c * 512]);
      gload16(w3e + (size_t)(n0 + row) * DM + k0 + skk, &B3s[c * 512]);
    }
    __syncthreads();
    #pragma unroll
    for (int kh = 0; kh < 2; ++kh) {
      int kb = kh * 32 + ((lane >> 4) * 8);
      short8 a[4], b1[4], b3[4];
      #pragma unroll
      for (int i = 0; i < 4; ++i) {
        a[i]  = *(const short8*)&As [(wm * 64 + i * 16 + (lane & 15)) * 64 + kb];
        b1[i] = *(const short8*)&B1s[(wn * 64 + i * 16 + (lane & 15)) * 64 + kb];
        b3[i] = *(const short8*)&B3s[(wn * 64 + i * 16 + (lane & 15)) * 64 + kb];
      }
      #pragma unroll
      for (int mi = 0; mi < 4; ++mi) {
        #pragma unroll
        for (int ni = 0; ni < 4; ++ni) {
          acc1[mi][ni] = __builtin_amdgcn_mfma_f32_16x16x32_bf16(a[mi], b1[ni], acc1[mi][ni], 0, 0, 0);
          acc3[mi][ni] = __builtin_amdgcn_mfma_f32_16x16x32_bf16(a[mi], b3[ni], acc3[mi][ni], 0, 0, 0);
        }
      }
    }
    __syncthreads();
  }
  int c0 = lane & 15, r0 = (lane >> 4) * 4;
  #pragma unroll
  for (int mi = 0; mi < 4; ++mi) {
    #pragma unroll
    for (int rg = 0; rg < 4; ++rg) {
      int r = wm * 64 + mi * 16 + r0 + rg;
      int gr = m0 + r;
      if (gr < cnt) {
        unsigned short* hrow = hg + (size_t)(off + gr) * DF + n0;
        #pragma unroll
        for (int ni = 0; ni < 4; ++ni) {
          float a1v = acc1[mi][ni][rg];
          float a3v = acc3[mi][ni][rg];
          float h = (a1v / (1.f + __expf(-a1v))) * a3v;
          hrow[wn * 64 + ni * 16 + c0] = f2bf(h);
        }
      }
    }
  }
}

// ---------------- FFN pass 2: ys[slot] = Hg[slot] * W2^T (plain fp32 stores) ----------------
__global__ __launch_bounds__(256) void k_ffn2(
    const unsigned short* __restrict__ hg,
    const unsigned short* __restrict__ w2b,
    const int* __restrict__ offs, const int* __restrict__ cnts,
    float* __restrict__ ys) {
  int e = blockIdx.z;
  int cnt = cnts[e];
  int m0 = blockIdx.y * 128;
  if (m0 >= cnt) return;
  int n0 = blockIdx.x * 128;
  int off = offs[e];
  __shared__ __align__(16) short As[128 * 64];
  __shared__ __align__(16) short Bs[128 * 64];
  int tid = threadIdx.x, lane = tid & 63, wid = tid >> 6;
  int srow = lane >> 3;
  int skk = (lane & 7) * 8;
  const unsigned short* w2e = w2b + (size_t)e * DM * DF;
  int wm = wid >> 1, wn = wid & 1;
  f32x4 acc[4][4] = {};
  for (int kt = 0; kt < DF / 64; ++kt) {
    int k0 = kt * 64;
    #pragma unroll
    for (int c4 = 0; c4 < 4; ++c4) {
      int c = wid * 4 + c4;
      int row = c * 8 + srow;
      int r = m0 + row; if (r > cnt - 1) r = cnt - 1;
      gload16(hg + (size_t)(off + r) * DF + k0 + skk, &As[c * 512]);
      gload16(w2e + (size_t)(n0 + row) * DF + k0 + skk, &Bs[c * 512]);
    }
    __syncthreads();
    #pragma unroll
    for (int kh = 0; kh < 2; ++kh) {
      int kb = kh * 32 + ((lane >> 4) * 8);
      short8 a[4], b[4];
      #pragma unroll
      for (int i = 0; i < 4; ++i) {
        a[i] = *(const short8*)&As[(wm * 64 + i * 16 + (lane & 15)) * 64 + kb];
        b[i] = *(const short8*)&Bs[(wn * 64 + i * 16 + (lane & 15)) * 64 + kb];
      }
      #pragma unroll
      for (int mi = 0; mi < 4; ++mi) {
        #pragma unroll
        for (int ni = 0; ni < 4; ++ni)
          acc[mi][ni] = __builtin_amdgcn_mfma_f32_16x16x32_bf16(a[mi], b[ni], acc[mi][ni], 0, 0, 0);
      }
    }
    __syncthreads();
  }
  int c0 = lane & 15, r0 = (lane >> 4) * 4;
  #pragma unroll
  for (int mi = 0; mi < 4; ++mi) {
    #pragma unroll
    for (int rg = 0; rg < 4; ++rg) {
      int r = wm * 64 + mi * 16 + r0 + rg;
      int gr = m0 + r;
      if (gr < cnt) {
        float* yrow = ys + (size_t)(off + gr) * DM + n0;
        #pragma unroll
        for (int ni = 0; ni < 4; ++ni)
          yrow[wn * 64 + ni * 16 + c0] = acc[mi][ni][rg];
      }
    }
  }
}

// ---------------- gather: out[t] = g0*ys[pos0] + g1*ys[pos1] (full overwrite) ----------------
__global__ void k_gather(const float* __restrict__ ys, const int* __restrict__ pos,
                         const float2* __restrict__ gts, float* __restrict__ out) {
  int idx = blockIdx.x * blockDim.x + threadIdx.x;   // over NT*DM/4
  int t = idx >> 8;                                  // DM/4 = 256 float4 per token
  int d4 = idx & 255;
  float2 g = gts[t];
  const float4* y0 = (const float4*)(ys + (size_t)pos[2 * t] * DM) + d4;
  const float4* y1 = (const float4*)(ys + (size_t)pos[2 * t + 1] * DM) + d4;
  float4 a = *y0, b = *y1, o;
  o.x = g.x * a.x + g.y * b.x;
  o.y = g.x * a.y + g.y * b.y;
  o.z = g.x * a.z + g.y * b.z;
  o.w = g.x * a.w + g.y * b.w;
  ((float4*)out)[idx] = o;
}

// ---------------- workspace layout (bytes) ----------------
// 0        : ctrl (cntb@0, cnt1@32, offs@96, imp@128, z2@160)
// 4096     : epack  int[8192]
// 36864    : gts    float2[8192]
// 102400   : btok   int[16384]
// 167936   : pos    int[16384]
// 233472   : x_bf16   (16.78 MB)
// 17010688 : W1_bf16  (33.55 MB)   <- ys fp32 (67.1 MB) aliases W1+W3 after ffn1
// 50565120 : W3_bf16  (33.55 MB)
// 84119552 : W2_bf16  (33.55 MB)
// 117673984: Hg bf16  (67.11 MB)   -> total 184782848 B (~176 MiB)

extern "C" void kernel_launch(void* const* d_in, const int* in_sizes, int n_in,
                              void* d_out, int out_size, void* d_ws, size_t ws_size,
                              hipStream_t stream) {
  const float* x  = (const float*)d_in[0];
  const float* wr = (const float*)d_in[1];
  const float* w1 = (const float*)d_in[2];
  const float* w3 = (const float*)d_in[3];
  const float* w2 = (const float*)d_in[4];
  float* out = (float*)d_out;

  uint8_t* ws = (uint8_t*)d_ws;
  int*    cntb   = (int*)(ws + 0);
  int*    cnt1   = (int*)(ws + 32);
  int*    offs   = (int*)(ws + 96);
  float*  imp    = (float*)(ws + 128);
  float*  z2     = (float*)(ws + 160);
  int*    epack  = (int*)(ws + 4096);
  float2* gts    = (float2*)(ws + 36864);
  int*    btok   = (int*)(ws + 102400);
  int*    pos    = (int*)(ws + 167936);
  unsigned short* xbf  = (unsigned short*)(ws + 233472);
  unsigned short* w1bf = (unsigned short*)(ws + 17010688);
  unsigned short* w3bf = (unsigned short*)(ws + 50565120);
  unsigned short* w2bf = (unsigned short*)(ws + 84119552);
  unsigned short* hg   = (unsigned short*)(ws + 117673984);
  float*          ysb  = (float*)(ws + 17010688);   // aliases w1bf+w3bf (dead after ffn1)

  hipMemsetAsync(ws, 0, 4096, stream);

  k_cvt<<<2048, 256, 0, stream>>>((const float4*)x,  (ushort4*)xbf,  NT * DM / 4);
  k_cvt<<<4096, 256, 0, stream>>>((const float4*)w1, (ushort4*)w1bf, 8 * DF * DM / 4);
  k_cvt<<<4096, 256, 0, stream>>>((const float4*)w3, (ushort4*)w3bf, 8 * DF * DM / 4);
  k_cvt<<<4096, 256, 0, stream>>>((const float4*)w2, (ushort4*)w2bf, 8 * DM * DF / 4);

  k_router<<<NT / 4, 256, 0, stream>>>(x, wr, cntb, cnt1, imp, z2, epack, gts);
  k_finalize<<<1, 64, 0, stream>>>(cntb, cnt1, imp, z2, offs, out + (size_t)NT * DM);
  k_scatter<<<8, 64, 0, stream>>>(epack, gts, offs, btok, pos);

  k_ffn1<<<dim3(16, 64, 8), 256, 0, stream>>>(xbf, w1bf, w3bf, offs, cntb, btok, hg);
  k_ffn2<<<dim3(8, 64, 8), 256, 0, stream>>>(hg, w2bf, offs, cntb, hg /*unused*/ == nullptr ? nullptr : ysb);
  k_gather<<<NT * DM / 4 / 256, 256, 0, stream>>>(ysb, pos, gts, out);
}

// Round 3
// 727.787 us; speedup vs baseline: 2.2062x; 2.2062x over previous
//
#include <hip/hip_runtime.h>
#include <stdint.h>

#define NT 8192      // tokens
#define DM 1024      // d_model
#define DF 2048      // d_ff
#define RT_BLOCKS 256

typedef __attribute__((ext_vector_type(8))) short short8;
typedef __attribute__((ext_vector_type(4))) float f32x4;

__device__ __forceinline__ unsigned short f2bf(float f) {
  uint32_t x = __float_as_uint(f);
  return (unsigned short)((x + 0x7fffu + ((x >> 16) & 1u)) >> 16);
}

__device__ __forceinline__ void gload16(const void* g, void* l) {
  __builtin_amdgcn_global_load_lds(
      (const __attribute__((address_space(1))) uint32_t*)g,
      (__attribute__((address_space(3))) uint32_t*)l, 16, 0, 0);
}

// ---------------- fp32 -> bf16 (RNE) ----------------
__global__ void k_cvt(const float4* __restrict__ src, ushort4* __restrict__ dst, int n4) {
  int i = blockIdx.x * blockDim.x + threadIdx.x;
  int st = gridDim.x * blockDim.x;
  for (; i < n4; i += st) {
    float4 v = src[i];
    ushort4 o;
    o.x = f2bf(v.x); o.y = f2bf(v.y); o.z = f2bf(v.z); o.w = f2bf(v.w);
    dst[i] = o;
  }
}

// ---------------- router: logits, softmax, top2; hierarchical loss reduction ----------------
__global__ void k_router(const float* __restrict__ x, const float* __restrict__ wr,
                         int* cntb, int* cnt1, float* imp, float* z2,
                         int* epack, float2* gts) {
  int lane = threadIdx.x & 63;
  int wid = threadIdx.x >> 6;
  const float4* w4 = (const float4*)wr;

  // per-wave partial accumulators (valid on lane 0)
  float imp_acc[8] = {0.f, 0.f, 0.f, 0.f, 0.f, 0.f, 0.f, 0.f};
  float z2_acc = 0.f;
  int cb_acc[8] = {0, 0, 0, 0, 0, 0, 0, 0};
  int c1_acc[8] = {0, 0, 0, 0, 0, 0, 0, 0};

  for (int t = blockIdx.x * 4 + wid; t < NT; t += RT_BLOCKS * 4) {
    const float4* x4 = (const float4*)(x + (size_t)t * DM);
    float p[8];
    #pragma unroll
    for (int e = 0; e < 8; ++e) p[e] = 0.f;
    #pragma unroll
    for (int j = 0; j < 4; ++j) {
      float4 xv = x4[lane + 64 * j];
      #pragma unroll
      for (int e = 0; e < 8; ++e) {
        float4 wv = w4[e * 256 + lane + 64 * j];
        p[e] += xv.x * wv.x + xv.y * wv.y + xv.z * wv.z + xv.w * wv.w;
      }
    }
    #pragma unroll
    for (int off = 32; off > 0; off >>= 1) {
      #pragma unroll
      for (int e = 0; e < 8; ++e) p[e] += __shfl_down(p[e], off);
    }
    if (lane == 0) {
      float m = p[0];
      #pragma unroll
      for (int e = 1; e < 8; ++e) m = fmaxf(m, p[e]);
      float pr[8], s = 0.f;
      #pragma unroll
      for (int e = 0; e < 8; ++e) { pr[e] = expf(p[e] - m); s += pr[e]; }
      float inv = 1.f / s;
      #pragma unroll
      for (int e = 0; e < 8; ++e) pr[e] *= inv;
      float z = m + logf(s);
      int e0 = 0; float b0 = p[0];
      #pragma unroll
      for (int e = 1; e < 8; ++e) { if (p[e] > b0) { b0 = p[e]; e0 = e; } }
      int e1 = -1; float b1 = -1e30f;
      #pragma unroll
      for (int e = 0; e < 8; ++e) { if (e != e0 && p[e] > b1) { b1 = p[e]; e1 = e; } }
      float p0 = 0.f, p1 = 0.f;
      #pragma unroll
      for (int e = 0; e < 8; ++e) {
        p0 = (e == e0) ? pr[e] : p0;
        p1 = (e == e1) ? pr[e] : p1;
      }
      float gs = p0 + p1 + 1e-9f;
      epack[t] = e0 | (e1 << 16);
      gts[t] = make_float2(p0 / gs, p1 / gs);
      z2_acc += z * z;
      #pragma unroll
      for (int e = 0; e < 8; ++e) {
        imp_acc[e] += pr[e];
        cb_acc[e] += (e == e0) + (e == e1);
        c1_acc[e] += (e == e0);
      }
    }
  }

  // block-level reduction, then one atomic per counter per block
  __shared__ float simp[4][8];
  __shared__ float sz2[4];
  __shared__ int scb[4][8];
  __shared__ int sc1[4][8];
  if (lane == 0) {
    #pragma unroll
    for (int e = 0; e < 8; ++e) { simp[wid][e] = imp_acc[e]; scb[wid][e] = cb_acc[e]; sc1[wid][e] = c1_acc[e]; }
    sz2[wid] = z2_acc;
  }
  __syncthreads();
  int tid = threadIdx.x;
  if (tid < 8) {
    float s = simp[0][tid] + simp[1][tid] + simp[2][tid] + simp[3][tid];
    int b = scb[0][tid] + scb[1][tid] + scb[2][tid] + scb[3][tid];
    int o = sc1[0][tid] + sc1[1][tid] + sc1[2][tid] + sc1[3][tid];
    atomicAdd(&imp[tid], s);
    atomicAdd(&cntb[tid], b);
    atomicAdd(&cnt1[tid], o);
  } else if (tid == 8) {
    atomicAdd(z2, sz2[0] + sz2[1] + sz2[2] + sz2[3]);
  }
}

// ---------------- offsets + scalar losses ----------------
__global__ void k_finalize(const int* cntb, const int* cnt1, const float* imp,
                           const float* z2, int* offs, float* otail) {
  if (threadIdx.x == 0 && blockIdx.x == 0) {
    int o = 0;
    for (int e = 0; e < 8; ++e) { offs[e] = o; o += cntb[e]; }
    otail[0] = 1e-3f * z2[0] / (float)NT;
    float aux = 0.f;
    for (int e = 0; e < 8; ++e)
      aux += (imp[e] / (float)NT) * ((float)cnt1[e] / (float)NT);
    otail[1] = aux * 8.f;
  }
}

// ---------------- deterministic stable scatter: 1 wave per expert ----------------
__global__ void k_scatter(const int* __restrict__ epack, const float2* __restrict__ gts,
                          const int* __restrict__ offs,
                          int* __restrict__ btok, int* __restrict__ pos) {
  int e = blockIdx.x;
  int lane = threadIdx.x;
  int base = offs[e];
  int run = 0;
  for (int j0 = 0; j0 < 2 * NT; j0 += 64) {
    int j = j0 + lane;
    int t = j >> 1;
    int ep = epack[t];
    int sel = (j & 1) ? (ep >> 16) : (ep & 0xffff);
    bool f = (sel == e);
    unsigned long long m = __ballot(f);
    int rank = __popcll(m & ((1ull << lane) - 1ull));
    if (f) {
      int slot = base + run + rank;
      btok[slot] = t;
      pos[j] = slot;
    }
    run += __popcll(m);
  }
}

// ---------------- FFN pass 1: Hg = silu(Xg*W1^T) * (Xg*W3^T) ----------------
__global__ __launch_bounds__(256) void k_ffn1(
    const unsigned short* __restrict__ xb,
    const unsigned short* __restrict__ w1b,
    const unsigned short* __restrict__ w3b,
    const int* __restrict__ offs, const int* __restrict__ cnts,
    const int* __restrict__ btok,
    unsigned short* __restrict__ hg) {
  int e = blockIdx.z;
  int cnt = cnts[e];
  int m0 = blockIdx.y * 128;
  if (m0 >= cnt) return;
  int n0 = blockIdx.x * 128;
  int off = offs[e];
  __shared__ __align__(16) short As[128 * 64];
  __shared__ __align__(16) short B1s[128 * 64];
  __shared__ __align__(16) short B3s[128 * 64];
  __shared__ int tok[128];
  int tid = threadIdx.x, lane = tid & 63, wid = tid >> 6;
  if (tid < 128) {
    int r = m0 + tid; if (r > cnt - 1) r = cnt - 1;
    tok[tid] = btok[off + r];
  }
  __syncthreads();
  int srow = lane >> 3;
  int skk = (lane & 7) * 8;
  const unsigned short* w1e = w1b + (size_t)e * DF * DM;
  const unsigned short* w3e = w3b + (size_t)e * DF * DM;
  int wm = wid >> 1, wn = wid & 1;
  f32x4 acc1[4][4] = {};
  f32x4 acc3[4][4] = {};
  for (int kt = 0; kt < DM / 64; ++kt) {
    int k0 = kt * 64;
    #pragma unroll
    for (int c4 = 0; c4 < 4; ++c4) {
      int c = wid * 4 + c4;
      int row = c * 8 + srow;
      gload16(xb + (size_t)tok[row] * DM + k0 + skk, &As[c * 512]);
      gload16(w1e + (size_t)(n0 + row) * DM + k0 + skk, &B1s[c * 512]);
      gload16(w3e + (size_t)(n0 + row) * DM + k0 + skk, &B3s[c * 512]);
    }
    __syncthreads();
    #pragma unroll
    for (int kh = 0; kh < 2; ++kh) {
      int kb = kh * 32 + ((lane >> 4) * 8);
      short8 a[4], b1[4], b3[4];
      #pragma unroll
      for (int i = 0; i < 4; ++i) {
        a[i]  = *(const short8*)&As [(wm * 64 + i * 16 + (lane & 15)) * 64 + kb];
        b1[i] = *(const short8*)&B1s[(wn * 64 + i * 16 + (lane & 15)) * 64 + kb];
        b3[i] = *(const short8*)&B3s[(wn * 64 + i * 16 + (lane & 15)) * 64 + kb];
      }
      #pragma unroll
      for (int mi = 0; mi < 4; ++mi) {
        #pragma unroll
        for (int ni = 0; ni < 4; ++ni) {
          acc1[mi][ni] = __builtin_amdgcn_mfma_f32_16x16x32_bf16(a[mi], b1[ni], acc1[mi][ni], 0, 0, 0);
          acc3[mi][ni] = __builtin_amdgcn_mfma_f32_16x16x32_bf16(a[mi], b3[ni], acc3[mi][ni], 0, 0, 0);
        }
      }
    }
    __syncthreads();
  }
  int c0 = lane & 15, r0 = (lane >> 4) * 4;
  #pragma unroll
  for (int mi = 0; mi < 4; ++mi) {
    #pragma unroll
    for (int rg = 0; rg < 4; ++rg) {
      int r = wm * 64 + mi * 16 + r0 + rg;
      int gr = m0 + r;
      if (gr < cnt) {
        unsigned short* hrow = hg + (size_t)(off + gr) * DF + n0;
        #pragma unroll
        for (int ni = 0; ni < 4; ++ni) {
          float a1v = acc1[mi][ni][rg];
          float a3v = acc3[mi][ni][rg];
          float h = (a1v / (1.f + __expf(-a1v))) * a3v;
          hrow[wn * 64 + ni * 16 + c0] = f2bf(h);
        }
      }
    }
  }
}

// ---------------- FFN pass 2: ys[slot] = Hg[slot] * W2^T (plain fp32 stores) ----------------
__global__ __launch_bounds__(256) void k_ffn2(
    const unsigned short* __restrict__ hg,
    const unsigned short* __restrict__ w2b,
    const int* __restrict__ offs, const int* __restrict__ cnts,
    float* __restrict__ ys) {
  int e = blockIdx.z;
  int cnt = cnts[e];
  int m0 = blockIdx.y * 128;
  if (m0 >= cnt) return;
  int n0 = blockIdx.x * 128;
  int off = offs[e];
  __shared__ __align__(16) short As[128 * 64];
  __shared__ __align__(16) short Bs[128 * 64];
  int tid = threadIdx.x, lane = tid & 63, wid = tid >> 6;
  int srow = lane >> 3;
  int skk = (lane & 7) * 8;
  const unsigned short* w2e = w2b + (size_t)e * DM * DF;
  int wm = wid >> 1, wn = wid & 1;
  f32x4 acc[4][4] = {};
  for (int kt = 0; kt < DF / 64; ++kt) {
    int k0 = kt * 64;
    #pragma unroll
    for (int c4 = 0; c4 < 4; ++c4) {
      int c = wid * 4 + c4;
      int row = c * 8 + srow;
      int r = m0 + row; if (r > cnt - 1) r = cnt - 1;
      gload16(hg + (size_t)(off + r) * DF + k0 + skk, &As[c * 512]);
      gload16(w2e + (size_t)(n0 + row) * DF + k0 + skk, &Bs[c * 512]);
    }
    __syncthreads();
    #pragma unroll
    for (int kh = 0; kh < 2; ++kh) {
      int kb = kh * 32 + ((lane >> 4) * 8);
      short8 a[4], b[4];
      #pragma unroll
      for (int i = 0; i < 4; ++i) {
        a[i] = *(const short8*)&As[(wm * 64 + i * 16 + (lane & 15)) * 64 + kb];
        b[i] = *(const short8*)&Bs[(wn * 64 + i * 16 + (lane & 15)) * 64 + kb];
      }
      #pragma unroll
      for (int mi = 0; mi < 4; ++mi) {
        #pragma unroll
        for (int ni = 0; ni < 4; ++ni)
          acc[mi][ni] = __builtin_amdgcn_mfma_f32_16x16x32_bf16(a[mi], b[ni], acc[mi][ni], 0, 0, 0);
      }
    }
    __syncthreads();
  }
  int c0 = lane & 15, r0 = (lane >> 4) * 4;
  #pragma unroll
  for (int mi = 0; mi < 4; ++mi) {
    #pragma unroll
    for (int rg = 0; rg < 4; ++rg) {
      int r = wm * 64 + mi * 16 + r0 + rg;
      int gr = m0 + r;
      if (gr < cnt) {
        float* yrow = ys + (size_t)(off + gr) * DM + n0;
        #pragma unroll
        for (int ni = 0; ni < 4; ++ni)
          yrow[wn * 64 + ni * 16 + c0] = acc[mi][ni][rg];
      }
    }
  }
}

// ---------------- gather: out[t] = g0*ys[pos0] + g1*ys[pos1] (full overwrite) ----------------
__global__ void k_gather(const float* __restrict__ ys, const int* __restrict__ pos,
                         const float2* __restrict__ gts, float* __restrict__ out) {
  int idx = blockIdx.x * blockDim.x + threadIdx.x;   // over NT*DM/4
  int t = idx >> 8;                                  // DM/4 = 256 float4 per token
  int d4 = idx & 255;
  float2 g = gts[t];
  const float4* y0 = (const float4*)(ys + (size_t)pos[2 * t] * DM) + d4;
  const float4* y1 = (const float4*)(ys + (size_t)pos[2 * t + 1] * DM) + d4;
  float4 a = *y0, b = *y1, o;
  o.x = g.x * a.x + g.y * b.x;
  o.y = g.x * a.y + g.y * b.y;
  o.z = g.x * a.z + g.y * b.z;
  o.w = g.x * a.w + g.y * b.w;
  ((float4*)out)[idx] = o;
}

// ---------------- workspace layout (bytes) ----------------
// 0        : ctrl (cntb@0, cnt1@32, offs@96, imp@128, z2@160)
// 4096     : epack  int[8192]
// 36864    : gts    float2[8192]
// 102400   : btok   int[16384]
// 167936   : pos    int[16384]
// 233472   : x_bf16   (16.78 MB)
// 17010688 : W1_bf16  (33.55 MB)   <- ys fp32 (67.1 MB) aliases W1+W3 after ffn1
// 50565120 : W3_bf16  (33.55 MB)
// 84119552 : W2_bf16  (33.55 MB)
// 117673984: Hg bf16  (67.11 MB)   -> total 184782848 B (~176 MiB)

extern "C" void kernel_launch(void* const* d_in, const int* in_sizes, int n_in,
                              void* d_out, int out_size, void* d_ws, size_t ws_size,
                              hipStream_t stream) {
  const float* x  = (const float*)d_in[0];
  const float* wr = (const float*)d_in[1];
  const float* w1 = (const float*)d_in[2];
  const float* w3 = (const float*)d_in[3];
  const float* w2 = (const float*)d_in[4];
  float* out = (float*)d_out;

  uint8_t* ws = (uint8_t*)d_ws;
  int*    cntb   = (int*)(ws + 0);
  int*    cnt1   = (int*)(ws + 32);
  int*    offs   = (int*)(ws + 96);
  float*  imp    = (float*)(ws + 128);
  float*  z2     = (float*)(ws + 160);
  int*    epack  = (int*)(ws + 4096);
  float2* gts    = (float2*)(ws + 36864);
  int*    btok   = (int*)(ws + 102400);
  int*    pos    = (int*)(ws + 167936);
  unsigned short* xbf  = (unsigned short*)(ws + 233472);
  unsigned short* w1bf = (unsigned short*)(ws + 17010688);
  unsigned short* w3bf = (unsigned short*)(ws + 50565120);
  unsigned short* w2bf = (unsigned short*)(ws + 84119552);
  unsigned short* hg   = (unsigned short*)(ws + 117673984);
  float*          ysb  = (float*)(ws + 17010688);   // aliases w1bf+w3bf (dead after ffn1)

  hipMemsetAsync(ws, 0, 4096, stream);

  k_cvt<<<2048, 256, 0, stream>>>((const float4*)x,  (ushort4*)xbf,  NT * DM / 4);
  k_cvt<<<4096, 256, 0, stream>>>((const float4*)w1, (ushort4*)w1bf, 8 * DF * DM / 4);
  k_cvt<<<4096, 256, 0, stream>>>((const float4*)w3, (ushort4*)w3bf, 8 * DF * DM / 4);
  k_cvt<<<4096, 256, 0, stream>>>((const float4*)w2, (ushort4*)w2bf, 8 * DM * DF / 4);

  k_router<<<RT_BLOCKS, 256, 0, stream>>>(x, wr, cntb, cnt1, imp, z2, epack, gts);
  k_finalize<<<1, 64, 0, stream>>>(cntb, cnt1, imp, z2, offs, out + (size_t)NT * DM);
  k_scatter<<<8, 64, 0, stream>>>(epack, gts, offs, btok, pos);

  k_ffn1<<<dim3(16, 64, 8), 256, 0, stream>>>(xbf, w1bf, w3bf, offs, cntb, btok, hg);
  k_ffn2<<<dim3(8, 64, 8), 256, 0, stream>>>(hg, w2bf, offs, cntb, ysb);
  k_gather<<<NT * DM / 4 / 256, 256, 0, stream>>>(ysb, pos, gts, out);
}